// Round 9
// baseline (231.224 us; speedup 1.0000x reference)
//
#include <hip/hip_runtime.h>
#include <stdint.h>

typedef unsigned short u16;
typedef __attribute__((ext_vector_type(8))) short short8;
typedef __attribute__((ext_vector_type(4))) float floatx4;
typedef __attribute__((ext_vector_type(2))) float floatx2;

#define K_DIM 1024
#define N_DIM 1024
#define BK 32
#define NCHUNK 32
// fallback kernel params
#define BM 64
#define HCHUNK 16

__device__ __forceinline__ u16 f2b(float f) {
    union { float f; uint32_t i; } v; v.f = f;
    uint32_t u = v.i;
    return (u16)((u + 0x7FFFu + ((u >> 16) & 1u)) >> 16);   // RNE fp32->bf16
}
__device__ __forceinline__ float b2f(u16 u) {
    union { uint32_t i; float f; } v; v.i = ((uint32_t)u) << 16; return v.f;
}

// ---------- kernel 1: W fp32 -> bf16, packed in MFMA-fragment order ----------
// packed[(tile*32 + kc)*512 + lane*8 + j] = bf16(W[tile*16 + (lane&15)][kc*32 + (lane>>4)*8 + j])
__global__ __launch_bounds__(256) void pack_w_kernel(const float* __restrict__ w,
                                                     u16* __restrict__ wpk) {
    int gid  = blockIdx.x * 256 + threadIdx.x;
    int lane = gid & 63;
    int kc   = (gid >> 6) & 31;
    int tile = gid >> 11;
    int n = tile * 16 + (lane & 15);
    int k = kc * 32 + (lane >> 4) * 8;
    const float* src = w + (size_t)n * K_DIM + k;
    floatx4 a = *(const floatx4*)(src);
    floatx4 b = *(const floatx4*)(src + 4);
    short8 o;
    o[0] = (short)f2b(a[0]); o[1] = (short)f2b(a[1]);
    o[2] = (short)f2b(a[2]); o[3] = (short)f2b(a[3]);
    o[4] = (short)f2b(b[0]); o[5] = (short)f2b(b[1]);
    o[6] = (short)f2b(b[2]); o[7] = (short)f2b(b[3]);
    *(short8*)(wpk + (size_t)gid * 8) = o;
}

// ---------- kernel 2a: 256x256 tile, 16 waves of 64x64, 3-slot LDS ring ------
// Unified-regfile fix for R8: acc[4][4]=64 AGPR + ~60 VGPR <= 128 total ->
// 4 waves/SIMD. LDS = 3 x 32KB chunk slots (A 16KB + B 16KB, FRAGMENT-ORDER
// linear layout -> all ds ops conflict-free, no swizzle). Per chunk: issue
// global loads for kc+2 -> compute slot kc%3 -> cvt+stage into slot (kc+2)%3
// -> lgkmcnt(0) + raw barrier (global pipeline never drained).
// Block mapping rb=bid&63, cb=bid>>6: the 4 col-blocks sharing an x-panel land
// on the SAME XCD (bids differ by 64 = 0 mod 8) -> x fetched once from HBM.
__global__ __launch_bounds__(1024) void gemm256v2_kernel(
    const float* __restrict__ x, const u16* __restrict__ wpk,
    const float* __restrict__ bias, u16* __restrict__ zout,
    float* __restrict__ gsum, float* __restrict__ gsum2)
{
    __shared__ __align__(16) char smem[3 * 32768];   // 3 slots: A 16KB + B 16KB
    __shared__ float ls_sum[256];
    __shared__ float ls_sum2[256];

    const int tid  = threadIdx.x;
    const int lane = tid & 63;
    const int wv   = tid >> 6;          // 0..15
    const int wr   = wv >> 2;           // 0..3  row-group
    const int wc   = wv & 3;            // 0..3  col-group
    const int q    = lane >> 4;
    const int rb   = blockIdx.x & 63;
    const int cb   = blockIdx.x >> 6;
    const int row0 = rb * 256;
    const int col0 = cb * 256;

    if (tid < 256) { ls_sum[tid] = 0.0f; ls_sum2[tid] = 0.0f; }

    // ---- A: thread t loads x[row0 + t>>2][kc*32 + (t&3)*8 .. +7] (32B) ------
    const float* xb = x + (size_t)(row0 + (tid >> 2)) * K_DIM + ((tid & 3) << 3);
    // stage dest (fragment order): tile (tid>>6)=wv, lane slot (r&15)+(t&3)*16
    const int a_st = wv * 1024 + ((((tid >> 2) & 15) + (tid & 3) * 16) << 4);
    // ---- B: wave wv stages fragment (cb*16 + wv, kc) ----
    const u16* wb = wpk + ((size_t)(cb * 16 + wv) * 32) * 512 + lane * 8;
    const int b_st = 16384 + wv * 1024 + (lane << 4);

    floatx4 acc[4][4];
#pragma unroll
    for (int mi = 0; mi < 4; ++mi)
#pragma unroll
        for (int ni = 0; ni < 4; ++ni)
            acc[mi][ni] = (floatx4){0.0f, 0.0f, 0.0f, 0.0f};

    // ---- prologue: stage chunks 0,1 into slots 0,1 ----
#pragma unroll
    for (int c = 0; c < 2; ++c) {
        floatx4 a0 = *(const floatx4*)(xb + c * BK);
        floatx4 a1 = *(const floatx4*)(xb + c * BK + 4);
        short8 bv  = *(const short8*)(wb + (size_t)c * 512);
        short8 aw;
        aw[0] = (short)f2b(a0[0]); aw[1] = (short)f2b(a0[1]);
        aw[2] = (short)f2b(a0[2]); aw[3] = (short)f2b(a0[3]);
        aw[4] = (short)f2b(a1[0]); aw[5] = (short)f2b(a1[1]);
        aw[6] = (short)f2b(a1[2]); aw[7] = (short)f2b(a1[3]);
        *(short8*)(smem + c * 32768 + a_st) = aw;
        *(short8*)(smem + c * 32768 + b_st) = bv;
    }
    __syncthreads();   // slots 0,1 + ls init visible

#pragma unroll 1
    for (int kc = 0; kc < NCHUNK; ++kc) {
        const int slot_c = kc % 3;
        const int slot_w = (kc + 2) % 3;
        const bool pf = (kc + 2 < NCHUNK);

        // (1) issue global loads for chunk kc+2 (land during this chunk's MFMA)
        floatx4 a0, a1; short8 bv;
        if (pf) {
            a0 = *(const floatx4*)(xb + (kc + 2) * BK);
            a1 = *(const floatx4*)(xb + (kc + 2) * BK + 4);
            bv = *(const short8*)(wb + (size_t)(kc + 2) * 512);
        }

        // (2) compute chunk kc from slot_c (linear, conflict-free ds_reads)
        const char* As = smem + slot_c * 32768;
        short8 af[4], bf[4];
#pragma unroll
        for (int mi = 0; mi < 4; ++mi)
            af[mi] = *(const short8*)(As + (wr * 4 + mi) * 1024 + (lane << 4));
#pragma unroll
        for (int ni = 0; ni < 4; ++ni)
            bf[ni] = *(const short8*)(As + 16384 + (wc * 4 + ni) * 1024 + (lane << 4));
#pragma unroll
        for (int mi = 0; mi < 4; ++mi)
#pragma unroll
            for (int ni = 0; ni < 4; ++ni)
                acc[mi][ni] = __builtin_amdgcn_mfma_f32_16x16x32_bf16(
                    af[mi], bf[ni], acc[mi][ni], 0, 0, 0);

        // (3) convert + stage chunk kc+2 into slot_w (disjoint from kc, kc+1)
        if (pf) {
            short8 aw;
            aw[0] = (short)f2b(a0[0]); aw[1] = (short)f2b(a0[1]);
            aw[2] = (short)f2b(a0[2]); aw[3] = (short)f2b(a0[3]);
            aw[4] = (short)f2b(a1[0]); aw[5] = (short)f2b(a1[1]);
            aw[6] = (short)f2b(a1[2]); aw[7] = (short)f2b(a1[3]);
            *(short8*)(smem + slot_w * 32768 + a_st) = aw;
            *(short8*)(smem + slot_w * 32768 + b_st) = bv;
        }

        // (4) own ds ops drained, then raw barrier (vmcnt untouched)
        asm volatile("s_waitcnt lgkmcnt(0)" ::: "memory");
        __builtin_amdgcn_s_barrier();
        asm volatile("" ::: "memory");
    }

    // ---- bias ----
    float bias_v[4];
#pragma unroll
    for (int ni = 0; ni < 4; ++ni)
        bias_v[ni] = bias[col0 + wc * 64 + ni * 16 + (lane & 15)];
#pragma unroll
    for (int mi = 0; mi < 4; ++mi)
#pragma unroll
        for (int ni = 0; ni < 4; ++ni)
#pragma unroll
            for (int r = 0; r < 4; ++r)
                acc[mi][ni][r] += bias_v[ni];

    // ---- partial row stats (this block's 256 cols) ----
#pragma unroll
    for (int mi = 0; mi < 4; ++mi)
#pragma unroll
        for (int r = 0; r < 4; ++r) {
            float s = 0.0f, s2 = 0.0f;
#pragma unroll
            for (int ni = 0; ni < 4; ++ni) {
                float v = acc[mi][ni][r];
                s += v; s2 += v * v;
            }
#pragma unroll
            for (int m = 1; m < 16; m <<= 1) {
                s  += __shfl_xor(s,  m, 64);
                s2 += __shfl_xor(s2, m, 64);
            }
            if ((lane & 15) == 0) {
                int rl = wr * 64 + mi * 16 + (q << 2) + r;
                atomicAdd(&ls_sum[rl], s);
                atomicAdd(&ls_sum2[rl], s2);
            }
        }

    __syncthreads();
    if (tid < 256) {
        atomicAdd(&gsum[row0 + tid],  ls_sum[tid]);
        atomicAdd(&gsum2[row0 + tid], ls_sum2[tid]);
    }

    // ---- z store: 4 slices of 64 rows x 256 cols via LDS transpose ----
    char* zb = smem;   // 32KB, aliases slot 0 (K-loop done)
    for (int s4 = 0; s4 < 4; ++s4) {
        if (wr == s4) {
#pragma unroll
            for (int mi = 0; mi < 4; ++mi)
#pragma unroll
                for (int ni = 0; ni < 4; ++ni)
#pragma unroll
                    for (int r = 0; r < 4; ++r) {
                        int lr  = mi * 16 + (q << 2) + r;              // 0..63
                        int col = wc * 64 + ni * 16 + (lane & 15);     // 0..255
                        int phys = lr * 512 + ((col << 1) ^ (q << 5));
                        *(u16*)(zb + phys) = f2b(acc[mi][ni][r]);
                    }
        }
        __syncthreads();
#pragma unroll
        for (int it = 0; it < 2; ++it) {
            int row = tid >> 4;                    // 0..63
            int c8  = (tid & 15) + it * 16;        // 0..31
            int phys = row * 512 + ((c8 << 4) ^ (((row >> 2) & 3) << 5));
            short8 z8 = *(const short8*)(zb + phys);
            *(short8*)(zout + (size_t)(row0 + s4 * 64 + row) * N_DIM + col0 + c8 * 8) = z8;
        }
        __syncthreads();
    }
}

// ---------- kernel 2b: streaming LN apply (mean/rstd from global sums) -------
__global__ __launch_bounds__(256) void ln_apply_kernel(
    const u16* __restrict__ z, const float* __restrict__ y,
    const float* __restrict__ stats, const float* __restrict__ gamma,
    const float* __restrict__ beta, float* __restrict__ out)
{
    int g   = blockIdx.x * 256 + threadIdx.x;
    int row = g >> 7;
    int c8  = g & 127;
    float s  = stats[row];
    float s2 = stats[16384 + row];
    float mean = s * (1.0f / 1024.0f);
    float var  = s2 * (1.0f / 1024.0f) - mean * mean;
    float rs   = rsqrtf(var + 1e-5f);
    short8 z8 = *(const short8*)(z + (size_t)row * N_DIM + c8 * 8);
    const float* yp  = y     + (size_t)row * N_DIM + c8 * 8;
    const float* gp  = gamma + c8 * 8;
    const float* bpv = beta  + c8 * 8;
    float*       op  = out   + (size_t)row * N_DIM + c8 * 8;
    floatx4 y0 = *(const floatx4*)(yp);
    floatx4 y1 = *(const floatx4*)(yp + 4);
    floatx4 g0 = *(const floatx4*)(gp);
    floatx4 g1 = *(const floatx4*)(gp + 4);
    floatx4 b0 = *(const floatx4*)(bpv);
    floatx4 b1 = *(const floatx4*)(bpv + 4);
    floatx4 o0, o1;
#pragma unroll
    for (int e = 0; e < 4; ++e) {
        float zv = b2f((u16)z8[e]);
        o0[e] = ((zv - mean) * rs * g0[e] + b0[e] + y0[e]) * y0[e];
    }
#pragma unroll
    for (int e = 0; e < 4; ++e) {
        float zv = b2f((u16)z8[e + 4]);
        o1[e] = ((zv - mean) * rs * g1[e] + b1[e] + y1[e]) * y1[e];
    }
    *(floatx4*)(op)     = o0;
    *(floatx4*)(op + 4) = o1;
}

// ---------- fallback: verified R6 fused kernel (workspace too small) ---------
// Uses the OLD pack layout addressing: frag (ni,kc) of wave wv at
// wv*65536 + ni*16384 + kc*512 == tile(wv*4+ni): (tile*32+kc)*512 — identical.
__global__ __launch_bounds__(1024) void fused_gemm_ln_kernel(
    const float* __restrict__ x, const float* __restrict__ y,
    const u16* __restrict__ wpk, const float* __restrict__ bias,
    const float* __restrict__ gamma, const float* __restrict__ beta,
    float* __restrict__ out)
{
    __shared__ __align__(16) u16 lds16[HCHUNK * BM * BK];
    __shared__ __align__(16) u16 zbuf[16 * 1024];
    __shared__ float ls_sum[64];
    __shared__ float ls_sum2[64];
    __shared__ float ls_mean[64];
    __shared__ float ls_rs[64];

    const int tid  = threadIdx.x;
    const int lane = tid & 63;
    const int wv   = tid >> 6;
    const int q    = lane >> 4;
    const int row0 = blockIdx.x * BM;

    if (tid < 64) { ls_sum[tid] = 0.0f; ls_sum2[tid] = 0.0f; }

    const int sr = tid >> 4;
    const int sk = (tid & 15) << 1;
    const float* s_src = x + (size_t)(row0 + sr) * K_DIM + sk;
    const int s_qs  = (sk >> 3) ^ ((sr >> 1) & 3);
    const int s_off = sr * 64 + s_qs * 16 + (sk & 7) * 2;

    const u16* bp = wpk + (size_t)wv * 65536 + lane * 8;
    const int a_base = (lane & 15) * 64 + (q ^ (((lane & 15) >> 1) & 3)) * 16;

    floatx4 acc[4][4];
#pragma unroll
    for (int mi = 0; mi < 4; ++mi)
#pragma unroll
        for (int ni = 0; ni < 4; ++ni)
            acc[mi][ni] = (floatx4){0.0f, 0.0f, 0.0f, 0.0f};

#pragma unroll 4
    for (int c = 0; c < HCHUNK; ++c) {
        floatx2 v = *(const floatx2*)(s_src + c * BK);
        uint32_t p = (uint32_t)f2b(v[0]) | ((uint32_t)f2b(v[1]) << 16);
        *(uint32_t*)((char*)lds16 + c * 4096 + s_off) = p;
    }
    short8 bfr[2][4];
#pragma unroll
    for (int ni = 0; ni < 4; ++ni)
        bfr[0][ni] = *(const short8*)(bp + ni * 16384);
    __syncthreads();

    for (int half = 0; half < 2; ++half) {
        if (half == 1) {
            __syncthreads();
#pragma unroll 4
            for (int c = 0; c < HCHUNK; ++c) {
                floatx2 v = *(const floatx2*)(s_src + (HCHUNK + c) * BK);
                uint32_t p = (uint32_t)f2b(v[0]) | ((uint32_t)f2b(v[1]) << 16);
                *(uint32_t*)((char*)lds16 + c * 4096 + s_off) = p;
            }
            __syncthreads();
        }
#pragma unroll 2
        for (int c = 0; c < HCHUNK; ++c) {
            const int kc  = half * HCHUNK + c;
            const int cur = kc & 1;
            const int nxt = cur ^ 1;
            const char* ab = (const char*)lds16 + c * 4096;
            short8 af0 = *(const short8*)(ab + a_base);
            short8 af1 = *(const short8*)(ab + a_base + 1024);
            short8 af2 = *(const short8*)(ab + a_base + 2048);
            short8 af3 = *(const short8*)(ab + a_base + 3072);
            const int kn = (kc + 1 < NCHUNK) ? (kc + 1) : kc;
#pragma unroll
            for (int ni = 0; ni < 4; ++ni)
                bfr[nxt][ni] = *(const short8*)(bp + ni * 16384 + kn * 512);
#pragma unroll
            for (int ni = 0; ni < 4; ++ni) {
                acc[0][ni] = __builtin_amdgcn_mfma_f32_16x16x32_bf16(af0, bfr[cur][ni], acc[0][ni], 0, 0, 0);
                acc[1][ni] = __builtin_amdgcn_mfma_f32_16x16x32_bf16(af1, bfr[cur][ni], acc[1][ni], 0, 0, 0);
                acc[2][ni] = __builtin_amdgcn_mfma_f32_16x16x32_bf16(af2, bfr[cur][ni], acc[2][ni], 0, 0, 0);
                acc[3][ni] = __builtin_amdgcn_mfma_f32_16x16x32_bf16(af3, bfr[cur][ni], acc[3][ni], 0, 0, 0);
            }
        }
    }

    float bias_v[4];
#pragma unroll
    for (int ni = 0; ni < 4; ++ni)
        bias_v[ni] = bias[(wv << 6) + (ni << 4) + (lane & 15)];
#pragma unroll
    for (int mi = 0; mi < 4; ++mi)
#pragma unroll
        for (int ni = 0; ni < 4; ++ni)
#pragma unroll
            for (int r = 0; r < 4; ++r)
                acc[mi][ni][r] += bias_v[ni];

    __syncthreads();

#pragma unroll
    for (int mi = 0; mi < 4; ++mi)
#pragma unroll
        for (int r = 0; r < 4; ++r) {
            float s = 0.0f, s2 = 0.0f;
#pragma unroll
            for (int ni = 0; ni < 4; ++ni) {
                float v = acc[mi][ni][r];
                s += v; s2 += v * v;
            }
#pragma unroll
            for (int m = 1; m < 16; m <<= 1) {
                s  += __shfl_xor(s,  m, 64);
                s2 += __shfl_xor(s2, m, 64);
            }
            if ((lane & 15) == 0) {
                int rl = (mi << 4) + (q << 2) + r;
                atomicAdd(&ls_sum[rl], s);
                atomicAdd(&ls_sum2[rl], s2);
            }
        }

    __syncthreads();
    if (tid < 64) {
        float mean = ls_sum[tid] * (1.0f / 1024.0f);
        float var  = ls_sum2[tid] * (1.0f / 1024.0f) - mean * mean;
        ls_mean[tid] = mean;
        ls_rs[tid]   = rsqrtf(var + 1e-5f);
    }

    for (int mi = 0; mi < 4; ++mi) {
#pragma unroll
        for (int ni = 0; ni < 4; ++ni)
#pragma unroll
            for (int r = 0; r < 4; ++r) {
                int lr   = (q << 2) + r;
                int lin  = (((wv << 6) + (ni << 4) + (lane & 15)) << 1);
                int phys = lr * 2048 + (lin ^ (q << 5));
                *(u16*)((char*)zbuf + phys) = f2b(acc[mi][ni][r]);
            }
        __syncthreads();
#pragma unroll
        for (int it = 0; it < 2; ++it) {
            int row  = (tid >> 7) + (it << 3);
            int c8   = tid & 127;
            int phys = row * 2048 + ((c8 << 4) ^ (((row >> 2) & 3) << 5));
            short8 z8 = *(const short8*)((const char*)zbuf + phys);
            int grow  = row0 + (mi << 4) + row;
            float mean = ls_mean[(mi << 4) + row];
            float rs   = ls_rs[(mi << 4) + row];
            const float* yp = y     + (size_t)grow * N_DIM + c8 * 8;
            const float* gp = gamma + c8 * 8;
            const float* bpv = beta + c8 * 8;
            float*       op = out   + (size_t)grow * N_DIM + c8 * 8;
            floatx4 y0 = *(const floatx4*)(yp);
            floatx4 y1 = *(const floatx4*)(yp + 4);
            floatx4 g0 = *(const floatx4*)(gp);
            floatx4 g1 = *(const floatx4*)(gp + 4);
            floatx4 b0 = *(const floatx4*)(bpv);
            floatx4 b1 = *(const floatx4*)(bpv + 4);
            floatx4 o0, o1;
#pragma unroll
            for (int e = 0; e < 4; ++e) {
                float zv = b2f((u16)z8[e]);
                o0[e] = ((zv - mean) * rs * g0[e] + b0[e] + y0[e]) * y0[e];
            }
#pragma unroll
            for (int e = 0; e < 4; ++e) {
                float zv = b2f((u16)z8[e + 4]);
                o1[e] = ((zv - mean) * rs * g1[e] + b1[e] + y1[e]) * y1[e];
            }
            *(floatx4*)(op)     = o0;
            *(floatx4*)(op + 4) = o1;
        }
        __syncthreads();
    }
}

extern "C" void kernel_launch(void* const* d_in, const int* in_sizes, int n_in,
                              void* d_out, int out_size, void* d_ws, size_t ws_size,
                              hipStream_t stream) {
    const float* x     = (const float*)d_in[0];
    const float* y     = (const float*)d_in[1];
    const float* wgt   = (const float*)d_in[2];
    const float* bias  = (const float*)d_in[3];
    const float* gamma = (const float*)d_in[4];
    const float* beta  = (const float*)d_in[5];
    float* out = (float*)d_out;

    u16* wpk = (u16*)d_ws;                               // 2MB packed bf16 W
    const size_t WPK_BYTES   = 2u * 1024u * 1024u;
    const size_t STATS_BYTES = 128u * 1024u;             // 2 x 16384 fp32 sums
    const size_t Z_BYTES     = 32u * 1024u * 1024u;      // 16384x1024 bf16
    const int M = in_sizes[0] / K_DIM;                   // 16384

    pack_w_kernel<<<512, 256, 0, stream>>>(wgt, wpk);

    if (ws_size >= WPK_BYTES + STATS_BYTES + Z_BYTES) {
        float* stats = (float*)((char*)d_ws + WPK_BYTES);
        u16*   zws   = (u16*)((char*)d_ws + WPK_BYTES + STATS_BYTES);
        hipMemsetAsync(stats, 0, STATS_BYTES, stream);
        gemm256v2_kernel<<<(M / 256) * 4, 1024, 0, stream>>>(
            x, wpk, bias, zws, stats, stats + 16384);
        ln_apply_kernel<<<M * (N_DIM / 8) / 256, 256, 0, stream>>>(
            zws, y, stats, gamma, beta, out);
    } else {
        fused_gemm_ln_kernel<<<M / BM, 1024, 0, stream>>>(
            x, y, wpk, bias, gamma, beta, out);
    }
}

// Round 10
// 225.112 us; speedup vs baseline: 1.0272x; 1.0272x over previous
//
#include <hip/hip_runtime.h>
#include <stdint.h>

typedef unsigned short u16;
typedef __attribute__((ext_vector_type(8))) short short8;
typedef __attribute__((ext_vector_type(4))) float floatx4;
typedef __attribute__((ext_vector_type(2))) float floatx2;

#define K_DIM 1024
#define N_DIM 1024
#define BK 32
#define NCHUNK 32
// fallback kernel params
#define BM 64
#define HCHUNK 16

__device__ __forceinline__ u16 f2b(float f) {
    union { float f; uint32_t i; } v; v.f = f;
    uint32_t u = v.i;
    return (u16)((u + 0x7FFFu + ((u >> 16) & 1u)) >> 16);   // RNE fp32->bf16
}
__device__ __forceinline__ float b2f(u16 u) {
    union { uint32_t i; float f; } v; v.i = ((uint32_t)u) << 16; return v.f;
}

// async global->LDS DMA, 16B per lane: LDS dest = uniform base + lane*16,
// global src = per-lane address. Counts against vmcnt.
__device__ __forceinline__ void ldsdma16(const u16* g, char* l) {
    __builtin_amdgcn_global_load_lds(
        (const __attribute__((address_space(1))) void*)g,
        (__attribute__((address_space(3))) void*)l, 16, 0, 0);
}

__device__ __forceinline__ short8 cvt8(floatx4 a0, floatx4 a1) {
    short8 aw;
    aw[0] = (short)f2b(a0[0]); aw[1] = (short)f2b(a0[1]);
    aw[2] = (short)f2b(a0[2]); aw[3] = (short)f2b(a0[3]);
    aw[4] = (short)f2b(a1[0]); aw[5] = (short)f2b(a1[1]);
    aw[6] = (short)f2b(a1[2]); aw[7] = (short)f2b(a1[3]);
    return aw;
}

// ---------- kernel 1: W fp32 -> bf16, packed in MFMA-fragment order ----------
// packed[(tile*32 + kc)*512 + lane*8 + j] = bf16(W[tile*16 + (lane&15)][kc*32 + (lane>>4)*8 + j])
__global__ __launch_bounds__(256) void pack_w_kernel(const float* __restrict__ w,
                                                     u16* __restrict__ wpk) {
    int gid  = blockIdx.x * 256 + threadIdx.x;
    int lane = gid & 63;
    int kc   = (gid >> 6) & 31;
    int tile = gid >> 11;
    int n = tile * 16 + (lane & 15);
    int k = kc * 32 + (lane >> 4) * 8;
    const float* src = w + (size_t)n * K_DIM + k;
    floatx4 a = *(const floatx4*)(src);
    floatx4 b = *(const floatx4*)(src + 4);
    short8 o = cvt8(a, b);
    *(short8*)(wpk + (size_t)gid * 8) = o;
}

// ---------- kernel 2a: 256x256 tile, async-DMA 3-slot ring (T3+T4 style) -----
// Per chunk kc: ds_read frags(slot kc%3) | issue A(kc+2)->regs + B(kc+2) DMA
// into slot (kc+2)%3 | cvt+ds_write A(kc+1) into slot (kc+1)%3 | 16 MFMA
// (setprio) | lgkmcnt(0) + vmcnt(3) + s_barrier.  vmcnt(3) = keep exactly the
// 3 newest in-flight ops {A(kc+2)x2, B(kc+2)}, guaranteeing own B(kc+1) DMA
// landed BEFORE the barrier that publishes it (per-wave drain -> cross-wave
// safe). No vmcnt(0), no VGPR roundtrip for B, all LDS ops lane-linear.
__global__ __launch_bounds__(1024) void gemm256v3_kernel(
    const float* __restrict__ x, const u16* __restrict__ wpk,
    const float* __restrict__ bias, u16* __restrict__ zout,
    float* __restrict__ gsum, float* __restrict__ gsum2)
{
    __shared__ __align__(16) char smem[3 * 32768];   // slot: [A 16KB][B 16KB]
    __shared__ float ls_sum[256];
    __shared__ float ls_sum2[256];

    const int tid  = threadIdx.x;
    const int lane = tid & 63;
    const int wv   = tid >> 6;          // 0..15
    const int wr   = wv >> 2;           // 0..3  row-group
    const int wc   = wv & 3;            // 0..3  col-group
    const int q    = lane >> 4;
    const int rb   = blockIdx.x & 63;
    const int cb   = blockIdx.x >> 6;
    const int row0 = rb * 256;
    const int col0 = cb * 256;

    if (tid < 256) { ls_sum[tid] = 0.0f; ls_sum2[tid] = 0.0f; }

    // ---- A: lane l of wave wv handles x[row0 + wv*16 + (l&15)][kc*32 + (l>>4)*8 ..+7]
    //      -> LDS dest wv*1024 + l*16 (LINEAR: conflict-free ds_write_b128)
    const float* xb = x + (size_t)(row0 + wv * 16 + (lane & 15)) * K_DIM + ((lane >> 4) << 3);
    const int a_st = wv * 1024 + lane * 16;
    // ---- B: wave wv DMAs fragment tile (cb*16 + wv); per-lane src +lane*8 elems
    const u16* wb = wpk + ((size_t)(cb * 16 + wv) * 32) * 512 + lane * 8;

    floatx4 acc[4][4];
#pragma unroll
    for (int mi = 0; mi < 4; ++mi)
#pragma unroll
        for (int ni = 0; ni < 4; ++ni)
            acc[mi][ni] = (floatx4){0.0f, 0.0f, 0.0f, 0.0f};

    // ---- prologue: A(0) direct into slot0; pa=A(1) regs; B(0),B(1) DMA; drain ----
    {
        floatx4 a0 = *(const floatx4*)(xb);
        floatx4 a1 = *(const floatx4*)(xb + 4);
        *(short8*)(smem + a_st) = cvt8(a0, a1);
    }
    floatx4 pa0 = *(const floatx4*)(xb + 32);
    floatx4 pa1 = *(const floatx4*)(xb + 36);
    ldsdma16(wb,       smem + 0 * 32768 + 16384 + wv * 1024);
    ldsdma16(wb + 512, smem + 1 * 32768 + 16384 + wv * 1024);
    asm volatile("s_waitcnt vmcnt(0)" ::: "memory");
    __syncthreads();   // slots 0 (A+B), 1 (B) + ls init published

#pragma unroll 1
    for (int kc = 0; kc < NCHUNK; ++kc) {
        const int slot_c = kc % 3;            // read
        const int slot_a = (kc + 1) % 3;      // A write (read next iter)
        const int slot_b = (kc + 2) % 3;      // B DMA target
        const bool pf = (kc + 2 < NCHUNK);

        // (1) frags for this chunk (published by prev iter's vmcnt+barrier)
        const char* As = smem + slot_c * 32768;
        short8 af[4], bf[4];
#pragma unroll
        for (int mi = 0; mi < 4; ++mi)
            af[mi] = *(const short8*)(As + (wr * 4 + mi) * 1024 + lane * 16);
#pragma unroll
        for (int ni = 0; ni < 4; ++ni)
            bf[ni] = *(const short8*)(As + 16384 + (wc * 4 + ni) * 1024 + lane * 16);

        // (2) issue next-next loads: A->regs first, then B DMA (order matters
        //     for the vmcnt(3) count below)
        floatx4 na0, na1;
        if (pf) {
            na0 = *(const floatx4*)(xb + (kc + 2) * 32);
            na1 = *(const floatx4*)(xb + (kc + 2) * 32 + 4);
            ldsdma16(wb + (size_t)(kc + 2) * 512,
                     smem + slot_b * 32768 + 16384 + wv * 1024);
        }

        // (3) cvt + stage A(kc+1) from regs loaded last iter (~1 chunk deep)
        if (kc + 1 < NCHUNK)
            *(short8*)(smem + slot_a * 32768 + a_st) = cvt8(pa0, pa1);

        // (4) MFMA cluster
        __builtin_amdgcn_s_setprio(1);
#pragma unroll
        for (int mi = 0; mi < 4; ++mi)
#pragma unroll
            for (int ni = 0; ni < 4; ++ni)
                acc[mi][ni] = __builtin_amdgcn_mfma_f32_16x16x32_bf16(
                    af[mi], bf[ni], acc[mi][ni], 0, 0, 0);
        __builtin_amdgcn_s_setprio(0);

        // (5) rotate A pipeline
        if (pf) { pa0 = na0; pa1 = na1; }

        // (6) publish: own ds ops drained; own B(kc+1) DMA complete (counted,
        //     keeps the 3 ops of kc+2 in flight); then barrier.
        asm volatile("s_waitcnt lgkmcnt(0)" ::: "memory");
        if (pf) asm volatile("s_waitcnt vmcnt(3)" ::: "memory");
        else    asm volatile("s_waitcnt vmcnt(0)" ::: "memory");
        __builtin_amdgcn_s_barrier();
        asm volatile("" ::: "memory");
    }

    // ---- bias ----
    float bias_v[4];
#pragma unroll
    for (int ni = 0; ni < 4; ++ni)
        bias_v[ni] = bias[col0 + wc * 64 + ni * 16 + (lane & 15)];
#pragma unroll
    for (int mi = 0; mi < 4; ++mi)
#pragma unroll
        for (int ni = 0; ni < 4; ++ni)
#pragma unroll
            for (int r = 0; r < 4; ++r)
                acc[mi][ni][r] += bias_v[ni];

    // ---- partial row stats (this block's 256 cols) ----
#pragma unroll
    for (int mi = 0; mi < 4; ++mi)
#pragma unroll
        for (int r = 0; r < 4; ++r) {
            float s = 0.0f, s2 = 0.0f;
#pragma unroll
            for (int ni = 0; ni < 4; ++ni) {
                float v = acc[mi][ni][r];
                s += v; s2 += v * v;
            }
#pragma unroll
            for (int m = 1; m < 16; m <<= 1) {
                s  += __shfl_xor(s,  m, 64);
                s2 += __shfl_xor(s2, m, 64);
            }
            if ((lane & 15) == 0) {
                int rl = wr * 64 + mi * 16 + (q << 2) + r;
                atomicAdd(&ls_sum[rl], s);
                atomicAdd(&ls_sum2[rl], s2);
            }
        }

    __syncthreads();
    if (tid < 256) {
        atomicAdd(&gsum[row0 + tid],  ls_sum[tid]);
        atomicAdd(&gsum2[row0 + tid], ls_sum2[tid]);
    }

    // ---- z store: 4 slices of 64 rows x 256 cols via LDS transpose ----
    char* zb = smem;   // 32KB, aliases slot 0 (K-loop done)
    for (int s4 = 0; s4 < 4; ++s4) {
        if (wr == s4) {
#pragma unroll
            for (int mi = 0; mi < 4; ++mi)
#pragma unroll
                for (int ni = 0; ni < 4; ++ni)
#pragma unroll
                    for (int r = 0; r < 4; ++r) {
                        int lr  = mi * 16 + (q << 2) + r;              // 0..63
                        int col = wc * 64 + ni * 16 + (lane & 15);     // 0..255
                        int phys = lr * 512 + ((col << 1) ^ (q << 5));
                        *(u16*)(zb + phys) = f2b(acc[mi][ni][r]);
                    }
        }
        __syncthreads();
#pragma unroll
        for (int it = 0; it < 2; ++it) {
            int row = tid >> 4;                    // 0..63
            int c8  = (tid & 15) + it * 16;        // 0..31
            int phys = row * 512 + ((c8 << 4) ^ (((row >> 2) & 3) << 5));
            short8 z8 = *(const short8*)(zb + phys);
            *(short8*)(zout + (size_t)(row0 + s4 * 64 + row) * N_DIM + col0 + c8 * 8) = z8;
        }
        __syncthreads();
    }
}

// ---------- kernel 2b: streaming LN apply (mean/rstd from global sums) -------
__global__ __launch_bounds__(256) void ln_apply_kernel(
    const u16* __restrict__ z, const float* __restrict__ y,
    const float* __restrict__ stats, const float* __restrict__ gamma,
    const float* __restrict__ beta, float* __restrict__ out)
{
    int g   = blockIdx.x * 256 + threadIdx.x;
    int row = g >> 7;
    int c8  = g & 127;
    float s  = stats[row];
    float s2 = stats[16384 + row];
    float mean = s * (1.0f / 1024.0f);
    float var  = s2 * (1.0f / 1024.0f) - mean * mean;
    float rs   = rsqrtf(var + 1e-5f);
    short8 z8 = *(const short8*)(z + (size_t)row * N_DIM + c8 * 8);
    const float* yp  = y     + (size_t)row * N_DIM + c8 * 8;
    const float* gp  = gamma + c8 * 8;
    const float* bpv = beta  + c8 * 8;
    float*       op  = out   + (size_t)row * N_DIM + c8 * 8;
    floatx4 y0 = *(const floatx4*)(yp);
    floatx4 y1 = *(const floatx4*)(yp + 4);
    floatx4 g0 = *(const floatx4*)(gp);
    floatx4 g1 = *(const floatx4*)(gp + 4);
    floatx4 b0 = *(const floatx4*)(bpv);
    floatx4 b1 = *(const floatx4*)(bpv + 4);
    floatx4 o0, o1;
#pragma unroll
    for (int e = 0; e < 4; ++e) {
        float zv = b2f((u16)z8[e]);
        o0[e] = ((zv - mean) * rs * g0[e] + b0[e] + y0[e]) * y0[e];
    }
#pragma unroll
    for (int e = 0; e < 4; ++e) {
        float zv = b2f((u16)z8[e + 4]);
        o1[e] = ((zv - mean) * rs * g1[e] + b1[e] + y1[e]) * y1[e];
    }
    *(floatx4*)(op)     = o0;
    *(floatx4*)(op + 4) = o1;
}

// ---------- fallback: verified R6 fused kernel (workspace too small) ---------
// Old per-wv addressing wv*65536 + ni*16384 + kc*512 == ((wv*4+ni)*32+kc)*512
// == the tile-major pack layout. Identical bytes.
__global__ __launch_bounds__(1024) void fused_gemm_ln_kernel(
    const float* __restrict__ x, const float* __restrict__ y,
    const u16* __restrict__ wpk, const float* __restrict__ bias,
    const float* __restrict__ gamma, const float* __restrict__ beta,
    float* __restrict__ out)
{
    __shared__ __align__(16) u16 lds16[HCHUNK * BM * BK];
    __shared__ __align__(16) u16 zbuf[16 * 1024];
    __shared__ float ls_sum[64];
    __shared__ float ls_sum2[64];
    __shared__ float ls_mean[64];
    __shared__ float ls_rs[64];

    const int tid  = threadIdx.x;
    const int lane = tid & 63;
    const int wv   = tid >> 6;
    const int q    = lane >> 4;
    const int row0 = blockIdx.x * BM;

    if (tid < 64) { ls_sum[tid] = 0.0f; ls_sum2[tid] = 0.0f; }

    const int sr = tid >> 4;
    const int sk = (tid & 15) << 1;
    const float* s_src = x + (size_t)(row0 + sr) * K_DIM + sk;
    const int s_qs  = (sk >> 3) ^ ((sr >> 1) & 3);
    const int s_off = sr * 64 + s_qs * 16 + (sk & 7) * 2;

    const u16* bp = wpk + (size_t)wv * 65536 + lane * 8;
    const int a_base = (lane & 15) * 64 + (q ^ (((lane & 15) >> 1) & 3)) * 16;

    floatx4 acc[4][4];
#pragma unroll
    for (int mi = 0; mi < 4; ++mi)
#pragma unroll
        for (int ni = 0; ni < 4; ++ni)
            acc[mi][ni] = (floatx4){0.0f, 0.0f, 0.0f, 0.0f};

#pragma unroll 4
    for (int c = 0; c < HCHUNK; ++c) {
        floatx2 v = *(const floatx2*)(s_src + c * BK);
        uint32_t p = (uint32_t)f2b(v[0]) | ((uint32_t)f2b(v[1]) << 16);
        *(uint32_t*)((char*)lds16 + c * 4096 + s_off) = p;
    }
    short8 bfr[2][4];
#pragma unroll
    for (int ni = 0; ni < 4; ++ni)
        bfr[0][ni] = *(const short8*)(bp + ni * 16384);
    __syncthreads();

    for (int half = 0; half < 2; ++half) {
        if (half == 1) {
            __syncthreads();
#pragma unroll 4
            for (int c = 0; c < HCHUNK; ++c) {
                floatx2 v = *(const floatx2*)(s_src + (HCHUNK + c) * BK);
                uint32_t p = (uint32_t)f2b(v[0]) | ((uint32_t)f2b(v[1]) << 16);
                *(uint32_t*)((char*)lds16 + c * 4096 + s_off) = p;
            }
            __syncthreads();
        }
#pragma unroll 2
        for (int c = 0; c < HCHUNK; ++c) {
            const int kc  = half * HCHUNK + c;
            const int cur = kc & 1;
            const int nxt = cur ^ 1;
            const char* ab = (const char*)lds16 + c * 4096;
            short8 af0 = *(const short8*)(ab + a_base);
            short8 af1 = *(const short8*)(ab + a_base + 1024);
            short8 af2 = *(const short8*)(ab + a_base + 2048);
            short8 af3 = *(const short8*)(ab + a_base + 3072);
            const int kn = (kc + 1 < NCHUNK) ? (kc + 1) : kc;
#pragma unroll
            for (int ni = 0; ni < 4; ++ni)
                bfr[nxt][ni] = *(const short8*)(bp + ni * 16384 + kn * 512);
#pragma unroll
            for (int ni = 0; ni < 4; ++ni) {
                acc[0][ni] = __builtin_amdgcn_mfma_f32_16x16x32_bf16(af0, bfr[cur][ni], acc[0][ni], 0, 0, 0);
                acc[1][ni] = __builtin_amdgcn_mfma_f32_16x16x32_bf16(af1, bfr[cur][ni], acc[1][ni], 0, 0, 0);
                acc[2][ni] = __builtin_amdgcn_mfma_f32_16x16x32_bf16(af2, bfr[cur][ni], acc[2][ni], 0, 0, 0);
                acc[3][ni] = __builtin_amdgcn_mfma_f32_16x16x32_bf16(af3, bfr[cur][ni], acc[3][ni], 0, 0, 0);
            }
        }
    }

    float bias_v[4];
#pragma unroll
    for (int ni = 0; ni < 4; ++ni)
        bias_v[ni] = bias[(wv << 6) + (ni << 4) + (lane & 15)];
#pragma unroll
    for (int mi = 0; mi < 4; ++mi)
#pragma unroll
        for (int ni = 0; ni < 4; ++ni)
#pragma unroll
            for (int r = 0; r < 4; ++r)
                acc[mi][ni][r] += bias_v[ni];

    __syncthreads();

#pragma unroll
    for (int mi = 0; mi < 4; ++mi)
#pragma unroll
        for (int r = 0; r < 4; ++r) {
            float s = 0.0f, s2 = 0.0f;
#pragma unroll
            for (int ni = 0; ni < 4; ++ni) {
                float v = acc[mi][ni][r];
                s += v; s2 += v * v;
            }
#pragma unroll
            for (int m = 1; m < 16; m <<= 1) {
                s  += __shfl_xor(s,  m, 64);
                s2 += __shfl_xor(s2, m, 64);
            }
            if ((lane & 15) == 0) {
                int rl = (mi << 4) + (q << 2) + r;
                atomicAdd(&ls_sum[rl], s);
                atomicAdd(&ls_sum2[rl], s2);
            }
        }

    __syncthreads();
    if (tid < 64) {
        float mean = ls_sum[tid] * (1.0f / 1024.0f);
        float var  = ls_sum2[tid] * (1.0f / 1024.0f) - mean * mean;
        ls_mean[tid] = mean;
        ls_rs[tid]   = rsqrtf(var + 1e-5f);
    }

    for (int mi = 0; mi < 4; ++mi) {
#pragma unroll
        for (int ni = 0; ni < 4; ++ni)
#pragma unroll
            for (int r = 0; r < 4; ++r) {
                int lr   = (q << 2) + r;
                int lin  = (((wv << 6) + (ni << 4) + (lane & 15)) << 1);
                int phys = lr * 2048 + (lin ^ (q << 5));
                *(u16*)((char*)zbuf + phys) = f2b(acc[mi][ni][r]);
            }
        __syncthreads();
#pragma unroll
        for (int it = 0; it < 2; ++it) {
            int row  = (tid >> 7) + (it << 3);
            int c8   = tid & 127;
            int phys = row * 2048 + ((c8 << 4) ^ (((row >> 2) & 3) << 5));
            short8 z8 = *(const short8*)((const char*)zbuf + phys);
            int grow  = row0 + (mi << 4) + row;
            float mean = ls_mean[(mi << 4) + row];
            float rs   = ls_rs[(mi << 4) + row];
            const float* yp = y     + (size_t)grow * N_DIM + c8 * 8;
            const float* gp = gamma + c8 * 8;
            const float* bpv = beta + c8 * 8;
            float*       op = out   + (size_t)grow * N_DIM + c8 * 8;
            floatx4 y0 = *(const floatx4*)(yp);
            floatx4 y1 = *(const floatx4*)(yp + 4);
            floatx4 g0 = *(const floatx4*)(gp);
            floatx4 g1 = *(const floatx4*)(gp + 4);
            floatx4 b0 = *(const floatx4*)(bpv);
            floatx4 b1 = *(const floatx4*)(bpv + 4);
            floatx4 o0, o1;
#pragma unroll
            for (int e = 0; e < 4; ++e) {
                float zv = b2f((u16)z8[e]);
                o0[e] = ((zv - mean) * rs * g0[e] + b0[e] + y0[e]) * y0[e];
            }
#pragma unroll
            for (int e = 0; e < 4; ++e) {
                float zv = b2f((u16)z8[e + 4]);
                o1[e] = ((zv - mean) * rs * g1[e] + b1[e] + y1[e]) * y1[e];
            }
            *(floatx4*)(op)     = o0;
            *(floatx4*)(op + 4) = o1;
        }
        __syncthreads();
    }
}

extern "C" void kernel_launch(void* const* d_in, const int* in_sizes, int n_in,
                              void* d_out, int out_size, void* d_ws, size_t ws_size,
                              hipStream_t stream) {
    const float* x     = (const float*)d_in[0];
    const float* y     = (const float*)d_in[1];
    const float* wgt   = (const float*)d_in[2];
    const float* bias  = (const float*)d_in[3];
    const float* gamma = (const float*)d_in[4];
    const float* beta  = (const float*)d_in[5];
    float* out = (float*)d_out;

    u16* wpk = (u16*)d_ws;                               // 2MB packed bf16 W
    const size_t WPK_BYTES   = 2u * 1024u * 1024u;
    const size_t STATS_BYTES = 128u * 1024u;             // 2 x 16384 fp32 sums
    const size_t Z_BYTES     = 32u * 1024u * 1024u;      // 16384x1024 bf16
    const int M = in_sizes[0] / K_DIM;                   // 16384

    pack_w_kernel<<<512, 256, 0, stream>>>(wgt, wpk);

    if (ws_size >= WPK_BYTES + STATS_BYTES + Z_BYTES) {
        float* stats = (float*)((char*)d_ws + WPK_BYTES);
        u16*   zws   = (u16*)((char*)d_ws + WPK_BYTES + STATS_BYTES);
        hipMemsetAsync(stats, 0, STATS_BYTES, stream);
        gemm256v3_kernel<<<(M / 256) * 4, 1024, 0, stream>>>(
            x, wpk, bias, zws, stats, stats + 16384);
        ln_apply_kernel<<<M * (N_DIM / 8) / 256, 256, 0, stream>>>(
            zws, y, stats, gamma, beta, out);
    } else {
        fused_gemm_ln_kernel<<<M / BM, 1024, 0, stream>>>(
            x, y, wpk, bias, gamma, beta, out);
    }
}